// Round 1
// baseline (615.833 us; speedup 1.0000x reference)
//
#include <hip/hip_runtime.h>

#define L_NODES 16384
#define E_EDGES 131072
#define CDIM 512
#define HEADS 8
#define DHEAD 64
#define HID 1024

typedef __attribute__((ext_vector_type(8))) short bf16x8;
typedef __attribute__((ext_vector_type(4))) float f32x4;

__device__ inline unsigned short f2b(float f) {
    union { float f; unsigned int u; } v{f};
    unsigned int r = (v.u + 0x7fffu + ((v.u >> 16) & 1u)) >> 16;
    return (unsigned short)r;
}

// ---------------- LayerNorm (fp32 in -> bf16 out) ----------------
__global__ __launch_bounds__(256) void ln_bf16_kernel(
    const float* __restrict__ x, const float* __restrict__ g,
    const float* __restrict__ b, short* __restrict__ out)
{
    int row = blockIdx.x;
    int t = threadIdx.x;
    const float2* xr = (const float2*)(x + (size_t)row * CDIM);
    float2 v = xr[t];
    float s = v.x + v.y;
    float sq = v.x * v.x + v.y * v.y;
    for (int off = 32; off; off >>= 1) {
        s += __shfl_xor(s, off);
        sq += __shfl_xor(sq, off);
    }
    __shared__ float ss[4], sqs[4];
    int wave = t >> 6, lane = t & 63;
    if (lane == 0) { ss[wave] = s; sqs[wave] = sq; }
    __syncthreads();
    s = ss[0] + ss[1] + ss[2] + ss[3];
    sq = sqs[0] + sqs[1] + sqs[2] + sqs[3];
    float mu = s * (1.0f / CDIM);
    float var = sq * (1.0f / CDIM) - mu * mu;
    float inv = rsqrtf(var + 1e-5f);
    int c = t * 2;
    unsigned short h0 = f2b((v.x - mu) * inv * g[c] + b[c]);
    unsigned short h1 = f2b((v.y - mu) * inv * g[c + 1] + b[c + 1]);
    unsigned int packed = ((unsigned int)h1 << 16) | h0;
    *(unsigned int*)(out + (size_t)row * CDIM + c) = packed;
}

// ---------------- Transpose + fp32->bf16 convert: W[K][N] -> WT[N][K] ----------------
__global__ void transpose_bf16_kernel(const float* __restrict__ W, short* __restrict__ WT,
                                      int K, int N)
{
    __shared__ float tile[32][33];
    int n0 = blockIdx.x * 32, k0 = blockIdx.y * 32;
    int tx = threadIdx.x, ty = threadIdx.y; // 32 x 8
    for (int r = 0; r < 4; r++) {
        int k = ty + r * 8;
        tile[k][tx] = W[(size_t)(k0 + k) * N + n0 + tx];
    }
    __syncthreads();
    for (int r = 0; r < 4; r++) {
        int n = ty + r * 8;
        WT[(size_t)(n0 + n) * K + k0 + tx] = f2b(tile[tx][n]);
    }
}

// ---------------- bf16 MFMA GEMM: C[M][N] = A[M][K] @ B^T[N][K] + epilogue ----------------
// A: bf16 [M][K] row-major.  B: bf16 [N][K] row-major (pre-transposed weights).
// Epilogue: +bias, optional GELU(tanh), optional +residual(fp32), write fp32 and/or bf16.
__global__ __launch_bounds__(256) void gemm_bf16_kernel(
    const short* __restrict__ A, const short* __restrict__ B,
    const float* __restrict__ bias, const float* __restrict__ res,
    float* __restrict__ outf, short* __restrict__ outb,
    int M, int N, int K, int act)
{
    __shared__ short As[128 * 40];
    __shared__ short Bs[128 * 40];
    int t = threadIdx.x;
    int bm = blockIdx.y * 128, bn = blockIdx.x * 128;
    int wave = t >> 6, lane = t & 63;
    int wm = (wave & 1) * 64, wn = (wave >> 1) * 64;
    int crow = lane & 15, quad = lane >> 4;
    int sm = t >> 1, hf = t & 1;   // staging: row within tile, 16-elem half

    f32x4 acc[4][4] = {};

    for (int k0 = 0; k0 < K; k0 += 32) {
        const uint4* pa = (const uint4*)(A + (size_t)(bm + sm) * K + k0 + hf * 16);
        uint4 a0 = pa[0], a1 = pa[1];
        const uint4* pb = (const uint4*)(B + (size_t)(bn + sm) * K + k0 + hf * 16);
        uint4 b0 = pb[0], b1 = pb[1];
        __syncthreads();   // previous iteration's reads done before overwrite
        *(uint4*)&As[sm * 40 + hf * 16] = a0;
        *(uint4*)&As[sm * 40 + hf * 16 + 8] = a1;
        *(uint4*)&Bs[sm * 40 + hf * 16] = b0;
        *(uint4*)&Bs[sm * 40 + hf * 16 + 8] = b1;
        __syncthreads();
        bf16x8 af[4], bg[4];
#pragma unroll
        for (int i = 0; i < 4; i++)
            af[i] = *(const bf16x8*)&As[(wm + i * 16 + crow) * 40 + quad * 8];
#pragma unroll
        for (int j = 0; j < 4; j++)
            bg[j] = *(const bf16x8*)&Bs[(wn + j * 16 + crow) * 40 + quad * 8];
#pragma unroll
        for (int i = 0; i < 4; i++)
#pragma unroll
            for (int j = 0; j < 4; j++)
                acc[i][j] = __builtin_amdgcn_mfma_f32_16x16x32_bf16(af[i], bg[j], acc[i][j], 0, 0, 0);
    }

#pragma unroll
    for (int i = 0; i < 4; i++) {
#pragma unroll
        for (int j = 0; j < 4; j++) {
            int n = bn + wn + j * 16 + crow;
            float bi = bias ? bias[n] : 0.0f;
#pragma unroll
            for (int r = 0; r < 4; r++) {
                int mrow = bm + wm + i * 16 + quad * 4 + r;
                float val = acc[i][j][r] + bi;
                if (act) {
                    float u = 0.7978845608028654f * (val + 0.044715f * val * val * val);
                    val = 0.5f * val * (1.0f + tanhf(u));
                }
                if (res) val += res[(size_t)mrow * N + n];
                if (outf) outf[(size_t)mrow * N + n] = val;
                if (outb) outb[(size_t)mrow * N + n] = f2b(val);
            }
        }
    }
}

// ---------------- CSR build ----------------
__global__ void hist_kernel(const int* __restrict__ row_index, int* __restrict__ cnt)
{
    int e = blockIdx.x * 256 + threadIdx.x;
    if (e < E_EDGES) atomicAdd(&cnt[row_index[e]], 1);
}

__global__ void scan_kernel(const int* __restrict__ cnt, int* __restrict__ row_start,
                            int* __restrict__ cursor)
{
    int t = threadIdx.x; // 64 threads, 1 wave
    const int PER = L_NODES / 64; // 256
    int local = 0;
    for (int i = 0; i < PER; i++) local += cnt[t * PER + i];
    int v = local;
    for (int off = 1; off < 64; off <<= 1) {
        int u = __shfl_up(v, off);
        if (t >= off) v += u;
    }
    int run = v - local; // exclusive prefix
    for (int i = 0; i < PER; i++) {
        row_start[t * PER + i] = run;
        cursor[t * PER + i] = run;
        run += cnt[t * PER + i];
    }
    if (t == 63) row_start[L_NODES] = run;
}

__global__ void scatter_kernel(const int* __restrict__ row_index, int* __restrict__ cursor,
                               int* __restrict__ perm)
{
    int e = blockIdx.x * 256 + threadIdx.x;
    if (e < E_EDGES) {
        int p = atomicAdd(&cursor[row_index[e]], 1);
        perm[p] = e;
    }
}

// ---------------- Edge attention: one block per row, wave per head ----------------
__global__ __launch_bounds__(512) void attn_kernel(
    const float* __restrict__ q, const float* __restrict__ k, const float* __restrict__ v,
    const int* __restrict__ col_index, const int* __restrict__ to_col_index,
    const float* __restrict__ pos_att_bias, const float* __restrict__ dist,
    const float* __restrict__ pos, const float* __restrict__ col_pos,
    const float* __restrict__ Wvec, const float* __restrict__ bvec,
    const int* __restrict__ row_start, const int* __restrict__ perm,
    short* __restrict__ out_bf)
{
    int r = blockIdx.x;
    int t = threadIdx.x;         // 512 = H*DH
    int h = t >> 6;              // head = wave
    int c = t;                   // channel
    float qv = q[(size_t)r * CDIM + c];
    float wv0 = Wvec[c], wv1 = Wvec[CDIM + c], wv2 = Wvec[2 * CDIM + c];
    float bv = bvec[c];
    float p0 = pos[r * 3], p1 = pos[r * 3 + 1], p2 = pos[r * 3 + 2];
    int e0 = row_start[r], e1 = row_start[r + 1];
    float m = -1e30f, l = 0.0f, acc = 0.0f;
    for (int idx = e0; idx < e1; ++idx) {
        int e = perm[idx];
        int col = col_index[e];
        float kv = k[(size_t)col * CDIM + c];
        float vv = v[(size_t)col * CDIM + c];
        int tci = to_col_index[e];
        float dinv = 1.0f / dist[e];
        float r0 = (col_pos[tci * 3] - p0) * dinv;
        float r1 = (col_pos[tci * 3 + 1] - p1) * dinv;
        float r2 = (col_pos[tci * 3 + 2] - p2) * dinv;
        vv += r0 * wv0 + r1 * wv1 + r2 * wv2 + bv;
        float d = qv - kv;
        float sum = d * d;
        for (int off = 32; off; off >>= 1) sum += __shfl_xor(sum, off);
        float score = -sum * 0.125f + pos_att_bias[e * HEADS + h];
        float mn = fmaxf(m, score);
        float scale = __expf(m - mn);
        float pe = __expf(score - mn);
        l = l * scale + pe;
        acc = acc * scale + pe * vv;
        m = mn;
    }
    float o = (l > 0.0f) ? acc / l : 0.0f;
    out_bf[(size_t)r * CDIM + c] = f2b(o);
}

// ---------------- launch ----------------
extern "C" void kernel_launch(void* const* d_in, const int* in_sizes, int n_in,
                              void* d_out, int out_size, void* d_ws, size_t ws_size,
                              hipStream_t stream)
{
    const float* x            = (const float*)d_in[0];
    const int*   row_index    = (const int*)d_in[1];
    const int*   col_index    = (const int*)d_in[2];
    const int*   to_col_index = (const int*)d_in[3];
    const float* pos_att_bias = (const float*)d_in[5];
    const float* dist         = (const float*)d_in[6];
    const float* pos          = (const float*)d_in[7];
    const float* col_pos      = (const float*)d_in[8];
    const float* ln1_g = (const float*)d_in[9];
    const float* ln1_b = (const float*)d_in[10];
    const float* ln2_g = (const float*)d_in[11];
    const float* ln2_b = (const float*)d_in[12];
    const float* Wq = (const float*)d_in[13];  const float* bq = (const float*)d_in[14];
    const float* Wk = (const float*)d_in[15];  const float* bk = (const float*)d_in[16];
    const float* Wv = (const float*)d_in[17];  const float* bv = (const float*)d_in[18];
    const float* Wvec = (const float*)d_in[19]; const float* bvec = (const float*)d_in[20];
    const float* Wo = (const float*)d_in[21];  const float* bo = (const float*)d_in[22];
    const float* W1 = (const float*)d_in[23];  const float* b1 = (const float*)d_in[24];
    const float* W2 = (const float*)d_in[25];  const float* b2 = (const float*)d_in[26];

    char* ws = (char*)d_ws;
    size_t off = 0;
    auto alloc = [&](size_t bytes) -> void* {
        void* p = ws + off;
        off = (off + bytes + 255) & ~(size_t)255;
        return p;
    };
    const size_t LC = (size_t)L_NODES * CDIM;
    float* qf  = (float*)alloc(LC * 4);
    float* kf  = (float*)alloc(LC * 4);
    float* vf  = (float*)alloc(LC * 4);
    float* x1f = (float*)alloc(LC * 4);
    short* zbf = (short*)alloc(LC * 2);            // LN1 out, reused for LN2 out
    short* abf = (short*)alloc(LC * 2);            // attention out (bf16)
    short* wqT = (short*)alloc((size_t)CDIM * CDIM * 2);
    short* wkT = (short*)alloc((size_t)CDIM * CDIM * 2);
    short* wvT = (short*)alloc((size_t)CDIM * CDIM * 2);
    short* woT = (short*)alloc((size_t)CDIM * CDIM * 2);
    short* w1T = (short*)alloc((size_t)CDIM * HID * 2);
    short* w2T = (short*)alloc((size_t)HID * CDIM * 2);
    int* cnt       = (int*)alloc(L_NODES * 4);
    int* cursor    = (int*)alloc(L_NODES * 4);
    int* row_start = (int*)alloc((L_NODES + 1) * 4);
    int* perm      = (int*)alloc(E_EDGES * 4);
    short* hbf = (short*)qf;  // hidden bf16 (L x HID) overlays qf (dead after attention)

    hipMemsetAsync(cnt, 0, L_NODES * 4, stream);

    // weight transposes (fp32 -> bf16 [N][K])
    dim3 tb(32, 8);
    transpose_bf16_kernel<<<dim3(CDIM / 32, CDIM / 32), tb, 0, stream>>>(Wq, wqT, CDIM, CDIM);
    transpose_bf16_kernel<<<dim3(CDIM / 32, CDIM / 32), tb, 0, stream>>>(Wk, wkT, CDIM, CDIM);
    transpose_bf16_kernel<<<dim3(CDIM / 32, CDIM / 32), tb, 0, stream>>>(Wv, wvT, CDIM, CDIM);
    transpose_bf16_kernel<<<dim3(CDIM / 32, CDIM / 32), tb, 0, stream>>>(Wo, woT, CDIM, CDIM);
    transpose_bf16_kernel<<<dim3(HID / 32, CDIM / 32), tb, 0, stream>>>(W1, w1T, CDIM, HID);
    transpose_bf16_kernel<<<dim3(CDIM / 32, HID / 32), tb, 0, stream>>>(W2, w2T, HID, CDIM);

    // LN1
    ln_bf16_kernel<<<L_NODES, 256, 0, stream>>>(x, ln1_g, ln1_b, zbf);

    // QKV GEMMs: [16384,512] = zbf @ W^T
    dim3 g512(CDIM / 128, L_NODES / 128);
    gemm_bf16_kernel<<<g512, 256, 0, stream>>>(zbf, wqT, bq, nullptr, qf, nullptr, L_NODES, CDIM, CDIM, 0);
    gemm_bf16_kernel<<<g512, 256, 0, stream>>>(zbf, wkT, bk, nullptr, kf, nullptr, L_NODES, CDIM, CDIM, 0);
    gemm_bf16_kernel<<<g512, 256, 0, stream>>>(zbf, wvT, bv, nullptr, vf, nullptr, L_NODES, CDIM, CDIM, 0);

    // CSR build
    hist_kernel<<<E_EDGES / 256, 256, 0, stream>>>(row_index, cnt);
    scan_kernel<<<1, 64, 0, stream>>>(cnt, row_start, cursor);
    scatter_kernel<<<E_EDGES / 256, 256, 0, stream>>>(row_index, cursor, perm);

    // edge attention
    attn_kernel<<<L_NODES, 512, 0, stream>>>(qf, kf, vf, col_index, to_col_index,
                                             pos_att_bias, dist, pos, col_pos,
                                             Wvec, bvec, row_start, perm, abf);

    // Wo GEMM + residual -> x1
    gemm_bf16_kernel<<<g512, 256, 0, stream>>>(abf, woT, bo, x, x1f, nullptr, L_NODES, CDIM, CDIM, 0);

    // LN2
    ln_bf16_kernel<<<L_NODES, 256, 0, stream>>>(x1f, ln2_g, ln2_b, zbf);

    // FFN
    dim3 g1024(HID / 128, L_NODES / 128);
    gemm_bf16_kernel<<<g1024, 256, 0, stream>>>(zbf, w1T, b1, nullptr, nullptr, hbf, L_NODES, HID, CDIM, 1);
    gemm_bf16_kernel<<<g512, 256, 0, stream>>>(hbf, w2T, b2, x1f, (float*)d_out, nullptr, L_NODES, CDIM, HID, 0);
}

// Round 2
// 496.973 us; speedup vs baseline: 1.2392x; 1.2392x over previous
//
#include <hip/hip_runtime.h>

#define L_NODES 16384
#define E_EDGES 131072
#define CDIM 512
#define QKVDIM 1536
#define HEADS 8
#define DHEAD 64
#define HID 1024

typedef __attribute__((ext_vector_type(8))) short bf16x8;
typedef __attribute__((ext_vector_type(4))) float f32x4;

__device__ inline unsigned short f2b(float f) {
    union { float f; unsigned int u; } v{f};
    unsigned int r = (v.u + 0x7fffu + ((v.u >> 16) & 1u)) >> 16;
    return (unsigned short)r;
}
__device__ inline float b2f(unsigned short h) {
    union { unsigned int u; float f; } v;
    v.u = (unsigned int)h << 16;
    return v.f;
}

// async global->LDS, 16B per lane (wave-uniform base + lane*16 semantics)
__device__ inline void async_lds16(const void* g, void* l) {
    __builtin_amdgcn_global_load_lds(
        (const __attribute__((address_space(1))) unsigned int*)g,
        (__attribute__((address_space(3))) unsigned int*)l,
        16, 0, 0);
}

// ---------------- LayerNorm (fp32 in -> bf16 out) ----------------
__global__ __launch_bounds__(256) void ln_bf16_kernel(
    const float* __restrict__ x, const float* __restrict__ g,
    const float* __restrict__ b, short* __restrict__ out)
{
    int row = blockIdx.x;
    int t = threadIdx.x;
    const float2* xr = (const float2*)(x + (size_t)row * CDIM);
    float2 v = xr[t];
    float s = v.x + v.y;
    float sq = v.x * v.x + v.y * v.y;
    for (int off = 32; off; off >>= 1) {
        s += __shfl_xor(s, off);
        sq += __shfl_xor(sq, off);
    }
    __shared__ float ss[4], sqs[4];
    int wave = t >> 6, lane = t & 63;
    if (lane == 0) { ss[wave] = s; sqs[wave] = sq; }
    __syncthreads();
    s = ss[0] + ss[1] + ss[2] + ss[3];
    sq = sqs[0] + sqs[1] + sqs[2] + sqs[3];
    float mu = s * (1.0f / CDIM);
    float var = sq * (1.0f / CDIM) - mu * mu;
    float inv = rsqrtf(var + 1e-5f);
    int c = t * 2;
    unsigned short h0 = f2b((v.x - mu) * inv * g[c] + b[c]);
    unsigned short h1 = f2b((v.y - mu) * inv * g[c + 1] + b[c + 1]);
    unsigned int packed = ((unsigned int)h1 << 16) | h0;
    *(unsigned int*)(out + (size_t)row * CDIM + c) = packed;
}

// ---------------- Transpose + fp32->bf16 convert: W[K][N] -> WT[N][K] ----------------
__global__ void transpose_bf16_kernel(const float* __restrict__ W, short* __restrict__ WT,
                                      int K, int N)
{
    __shared__ float tile[32][33];
    int n0 = blockIdx.x * 32, k0 = blockIdx.y * 32;
    int tx = threadIdx.x, ty = threadIdx.y; // 32 x 8
    for (int r = 0; r < 4; r++) {
        int k = ty + r * 8;
        tile[k][tx] = W[(size_t)(k0 + k) * N + n0 + tx];
    }
    __syncthreads();
    for (int r = 0; r < 4; r++) {
        int n = ty + r * 8;
        WT[(size_t)(n0 + n) * K + k0 + tx] = f2b(tile[tx][n]);
    }
}

__global__ void pack_bias_kernel(const float* __restrict__ bq, const float* __restrict__ bk,
                                 const float* __restrict__ bv, float* __restrict__ out)
{
    int i = blockIdx.x * 256 + threadIdx.x;
    if (i < CDIM) out[i] = bq[i];
    else if (i < 2 * CDIM) out[i] = bk[i - CDIM];
    else out[i] = bv[i - 2 * CDIM];
}

// ---------------- bf16 MFMA GEMM (m97 structure): C[M][N] = A[M][K] @ B^T[N][K] ----------------
// A: bf16 [M][K]. B: bf16 [N][K]. BM=BN=128, BK=32. global_load_lds width-16 staging.
__global__ __launch_bounds__(256) void gemm_bf16_kernel(
    const short* __restrict__ A, const short* __restrict__ B,
    const float* __restrict__ bias, const float* __restrict__ res,
    float* __restrict__ outf, short* __restrict__ outb,
    int M, int N, int K, int act)
{
    __shared__ short As[128 * 32];   // unpadded: required by global_load_lds lane order
    __shared__ short Bs[128 * 32];
    int t = threadIdx.x;
    int bm = blockIdx.y * 128, bn = blockIdx.x * 128;
    int wave = t >> 6, lane = t & 63;
    int wm = (wave & 1) * 64, wn = (wave >> 1) * 64;
    int crow = lane & 15, quad = lane >> 4;

    f32x4 acc[4][4] = {};

    for (int k0 = 0; k0 < K; k0 += 32) {
#pragma unroll
        for (int c = 0; c < 2; c++) {
            int idx = c * 256 + t;
            int row = idx >> 2, chunk = idx & 3;
            async_lds16(A + (size_t)(bm + row) * K + k0 + chunk * 8,
                        (char*)As + c * 4096 + wave * 1024 + lane * 16);
            async_lds16(B + (size_t)(bn + row) * K + k0 + chunk * 8,
                        (char*)Bs + c * 4096 + wave * 1024 + lane * 16);
        }
        __syncthreads();   // drains vmcnt (loads visible) before any wave reads
        bf16x8 af[4], bg[4];
#pragma unroll
        for (int i = 0; i < 4; i++)
            af[i] = *(const bf16x8*)&As[(wm + i * 16 + crow) * 32 + quad * 8];
#pragma unroll
        for (int j = 0; j < 4; j++)
            bg[j] = *(const bf16x8*)&Bs[(wn + j * 16 + crow) * 32 + quad * 8];
#pragma unroll
        for (int i = 0; i < 4; i++)
#pragma unroll
            for (int j = 0; j < 4; j++)
                acc[i][j] = __builtin_amdgcn_mfma_f32_16x16x32_bf16(af[i], bg[j], acc[i][j], 0, 0, 0);
        __syncthreads();   // all reads done before next iteration overwrites
    }

#pragma unroll
    for (int i = 0; i < 4; i++) {
#pragma unroll
        for (int j = 0; j < 4; j++) {
            int n = bn + wn + j * 16 + crow;
            float bi = bias ? bias[n] : 0.0f;
#pragma unroll
            for (int r = 0; r < 4; r++) {
                int mrow = bm + wm + i * 16 + quad * 4 + r;
                float val = acc[i][j][r] + bi;
                if (act) {
                    float u = 0.7978845608028654f * (val + 0.044715f * val * val * val);
                    val = 0.5f * val * (1.0f + tanhf(u));
                }
                if (res) val += res[(size_t)mrow * N + n];
                if (outf) outf[(size_t)mrow * N + n] = val;
                if (outb) outb[(size_t)mrow * N + n] = f2b(val);
            }
        }
    }
}

// ---------------- CSR build ----------------
__global__ void hist_kernel(const int* __restrict__ row_index, int* __restrict__ cnt)
{
    int e = blockIdx.x * 256 + threadIdx.x;
    if (e < E_EDGES) atomicAdd(&cnt[row_index[e]], 1);
}

__global__ void scan_kernel(const int* __restrict__ cnt, int* __restrict__ row_start,
                            int* __restrict__ cursor)
{
    int t = threadIdx.x; // 64 threads, 1 wave
    const int PER = L_NODES / 64; // 256
    int local = 0;
    for (int i = 0; i < PER; i++) local += cnt[t * PER + i];
    int v = local;
    for (int off = 1; off < 64; off <<= 1) {
        int u = __shfl_up(v, off);
        if (t >= off) v += u;
    }
    int run = v - local; // exclusive prefix
    for (int i = 0; i < PER; i++) {
        row_start[t * PER + i] = run;
        cursor[t * PER + i] = run;
        run += cnt[t * PER + i];
    }
    if (t == 63) row_start[L_NODES] = run;
}

// scatter edge data packed by destination slot: (col, tci, dist_bits, e)
__global__ void scatter_kernel(const int* __restrict__ row_index, const int* __restrict__ col_index,
                               const int* __restrict__ to_col_index, const float* __restrict__ dist,
                               int* __restrict__ cursor, int4* __restrict__ epack)
{
    int e = blockIdx.x * 256 + threadIdx.x;
    if (e < E_EDGES) {
        int p = atomicAdd(&cursor[row_index[e]], 1);
        epack[p] = make_int4(col_index[e], to_col_index[e], __float_as_int(dist[e]), e);
    }
}

// ---------------- Edge attention: one block per row, wave per head ----------------
// qkv: bf16 [L][1536] (q | k | v)
__global__ __launch_bounds__(512) void attn_kernel(
    const short* __restrict__ qkv,
    const int4* __restrict__ epack,
    const float* __restrict__ pos_att_bias,
    const float* __restrict__ pos, const float* __restrict__ col_pos,
    const float* __restrict__ Wvec, const float* __restrict__ bvec,
    const int* __restrict__ row_start,
    short* __restrict__ out_bf)
{
    int r = blockIdx.x;
    int t = threadIdx.x;         // 512 = H*DH
    int h = t >> 6;              // head = wave
    int c = t;                   // channel
    float qv = b2f(((const unsigned short*)qkv)[(size_t)r * QKVDIM + c]);
    float wv0 = Wvec[c], wv1 = Wvec[CDIM + c], wv2 = Wvec[2 * CDIM + c];
    float bv = bvec[c];
    float p0 = pos[r * 3], p1 = pos[r * 3 + 1], p2 = pos[r * 3 + 2];
    int e0 = row_start[r], e1 = row_start[r + 1];
    float m = -1e30f, l = 0.0f, acc = 0.0f;
    const unsigned short* kvbase = (const unsigned short*)qkv;

    int idx = e0;
    for (; idx + 1 < e1; idx += 2) {
        int4 ea = epack[idx], eb = epack[idx + 1];
        size_t ba = (size_t)ea.x * QKVDIM + CDIM + c;
        size_t bb = (size_t)eb.x * QKVDIM + CDIM + c;
        float ka = b2f(kvbase[ba]);
        float va = b2f(kvbase[ba + CDIM]);
        float kb = b2f(kvbase[bb]);
        float vb = b2f(kvbase[bb + CDIM]);
        float biasa = pos_att_bias[ea.w * HEADS + h];
        float biasb = pos_att_bias[eb.w * HEADS + h];
        float dia = 1.0f / __int_as_float(ea.z);
        float dib = 1.0f / __int_as_float(eb.z);
        float ra0 = (col_pos[ea.y * 3] - p0) * dia;
        float ra1 = (col_pos[ea.y * 3 + 1] - p1) * dia;
        float ra2 = (col_pos[ea.y * 3 + 2] - p2) * dia;
        float rb0 = (col_pos[eb.y * 3] - p0) * dib;
        float rb1 = (col_pos[eb.y * 3 + 1] - p1) * dib;
        float rb2 = (col_pos[eb.y * 3 + 2] - p2) * dib;
        va += ra0 * wv0 + ra1 * wv1 + ra2 * wv2 + bv;
        vb += rb0 * wv0 + rb1 * wv1 + rb2 * wv2 + bv;
        float da = qv - ka, db = qv - kb;
        float sa = da * da, sb = db * db;
        for (int off = 32; off; off >>= 1) {
            sa += __shfl_xor(sa, off);
            sb += __shfl_xor(sb, off);
        }
        float s0 = -sa * 0.125f + biasa;
        float s1 = -sb * 0.125f + biasb;
        float mn = fmaxf(m, fmaxf(s0, s1));
        float scale = __expf(m - mn);
        float pa = __expf(s0 - mn);
        float pb = __expf(s1 - mn);
        l = l * scale + pa + pb;
        acc = acc * scale + pa * va + pb * vb;
        m = mn;
    }
    if (idx < e1) {
        int4 ea = epack[idx];
        size_t ba = (size_t)ea.x * QKVDIM + CDIM + c;
        float ka = b2f(kvbase[ba]);
        float va = b2f(kvbase[ba + CDIM]);
        float dia = 1.0f / __int_as_float(ea.z);
        float ra0 = (col_pos[ea.y * 3] - p0) * dia;
        float ra1 = (col_pos[ea.y * 3 + 1] - p1) * dia;
        float ra2 = (col_pos[ea.y * 3 + 2] - p2) * dia;
        va += ra0 * wv0 + ra1 * wv1 + ra2 * wv2 + bv;
        float da = qv - ka;
        float sa = da * da;
        for (int off = 32; off; off >>= 1) sa += __shfl_xor(sa, off);
        float s0 = -sa * 0.125f + pos_att_bias[ea.w * HEADS + h];
        float mn = fmaxf(m, s0);
        float scale = __expf(m - mn);
        float pa = __expf(s0 - mn);
        l = l * scale + pa;
        acc = acc * scale + pa * va;
        m = mn;
    }
    float o = (l > 0.0f) ? acc / l : 0.0f;
    out_bf[(size_t)r * CDIM + c] = f2b(o);
}

// ---------------- launch ----------------
extern "C" void kernel_launch(void* const* d_in, const int* in_sizes, int n_in,
                              void* d_out, int out_size, void* d_ws, size_t ws_size,
                              hipStream_t stream)
{
    const float* x            = (const float*)d_in[0];
    const int*   row_index    = (const int*)d_in[1];
    const int*   col_index    = (const int*)d_in[2];
    const int*   to_col_index = (const int*)d_in[3];
    const float* pos_att_bias = (const float*)d_in[5];
    const float* dist         = (const float*)d_in[6];
    const float* pos          = (const float*)d_in[7];
    const float* col_pos      = (const float*)d_in[8];
    const float* ln1_g = (const float*)d_in[9];
    const float* ln1_b = (const float*)d_in[10];
    const float* ln2_g = (const float*)d_in[11];
    const float* ln2_b = (const float*)d_in[12];
    const float* Wq = (const float*)d_in[13];  const float* bq = (const float*)d_in[14];
    const float* Wk = (const float*)d_in[15];  const float* bk = (const float*)d_in[16];
    const float* Wv = (const float*)d_in[17];  const float* bv = (const float*)d_in[18];
    const float* Wvec = (const float*)d_in[19]; const float* bvec = (const float*)d_in[20];
    const float* Wo = (const float*)d_in[21];  const float* bo = (const float*)d_in[22];
    const float* W1 = (const float*)d_in[23];  const float* b1 = (const float*)d_in[24];
    const float* W2 = (const float*)d_in[25];  const float* b2 = (const float*)d_in[26];

    char* ws = (char*)d_ws;
    size_t off = 0;
    auto alloc = [&](size_t bytes) -> void* {
        void* p = ws + off;
        off = (off + bytes + 255) & ~(size_t)255;
        return p;
    };
    const size_t LC = (size_t)L_NODES * CDIM;
    short* qkvb = (short*)alloc((size_t)L_NODES * QKVDIM * 2);  // q|k|v bf16
    float* x1f  = (float*)alloc(LC * 4);
    short* zbf  = (short*)alloc(LC * 2);            // LN1 out, reused for LN2 out
    short* abf  = (short*)alloc(LC * 2);            // attention out (bf16)
    short* wqkvT = (short*)alloc((size_t)QKVDIM * CDIM * 2);
    short* woT   = (short*)alloc((size_t)CDIM * CDIM * 2);
    short* w1T   = (short*)alloc((size_t)CDIM * HID * 2);
    short* w2T   = (short*)alloc((size_t)HID * CDIM * 2);
    float* bqkv  = (float*)alloc(QKVDIM * 4);
    int* cnt       = (int*)alloc(L_NODES * 4);
    int* cursor    = (int*)alloc(L_NODES * 4);
    int* row_start = (int*)alloc((L_NODES + 1) * 4);
    int4* epack    = (int4*)alloc((size_t)E_EDGES * 16);
    short* hbf = (short*)qkvb;  // hidden bf16 (L x HID) overlays qkvb (dead after attention)

    hipMemsetAsync(cnt, 0, L_NODES * 4, stream);

    // weight transposes (fp32 -> bf16 [N][K]); QKV concatenated along N
    dim3 tb(32, 8);
    transpose_bf16_kernel<<<dim3(CDIM / 32, CDIM / 32), tb, 0, stream>>>(Wq, wqkvT, CDIM, CDIM);
    transpose_bf16_kernel<<<dim3(CDIM / 32, CDIM / 32), tb, 0, stream>>>(Wk, wqkvT + (size_t)CDIM * CDIM, CDIM, CDIM);
    transpose_bf16_kernel<<<dim3(CDIM / 32, CDIM / 32), tb, 0, stream>>>(Wv, wqkvT + (size_t)2 * CDIM * CDIM, CDIM, CDIM);
    transpose_bf16_kernel<<<dim3(CDIM / 32, CDIM / 32), tb, 0, stream>>>(Wo, woT, CDIM, CDIM);
    transpose_bf16_kernel<<<dim3(HID / 32, CDIM / 32), tb, 0, stream>>>(W1, w1T, CDIM, HID);
    transpose_bf16_kernel<<<dim3(CDIM / 32, HID / 32), tb, 0, stream>>>(W2, w2T, HID, CDIM);
    pack_bias_kernel<<<QKVDIM / 256, 256, 0, stream>>>(bq, bk, bv, bqkv);

    // LN1
    ln_bf16_kernel<<<L_NODES, 256, 0, stream>>>(x, ln1_g, ln1_b, zbf);

    // fused QKV GEMM: [16384,1536] bf16
    dim3 gqkv(QKVDIM / 128, L_NODES / 128);
    gemm_bf16_kernel<<<gqkv, 256, 0, stream>>>(zbf, wqkvT, bqkv, nullptr, nullptr, qkvb,
                                               L_NODES, QKVDIM, CDIM, 0);

    // CSR build
    hist_kernel<<<E_EDGES / 256, 256, 0, stream>>>(row_index, cnt);
    scan_kernel<<<1, 64, 0, stream>>>(cnt, row_start, cursor);
    scatter_kernel<<<E_EDGES / 256, 256, 0, stream>>>(row_index, col_index, to_col_index, dist,
                                                      cursor, epack);

    // edge attention
    attn_kernel<<<L_NODES, 512, 0, stream>>>(qkvb, epack, pos_att_bias, pos, col_pos,
                                             Wvec, bvec, row_start, abf);

    // Wo GEMM + residual -> x1
    dim3 g512(CDIM / 128, L_NODES / 128);
    gemm_bf16_kernel<<<g512, 256, 0, stream>>>(abf, woT, bo, x, x1f, nullptr, L_NODES, CDIM, CDIM, 0);

    // LN2
    ln_bf16_kernel<<<L_NODES, 256, 0, stream>>>(x1f, ln2_g, ln2_b, zbf);

    // FFN
    dim3 g1024(HID / 128, L_NODES / 128);
    gemm_bf16_kernel<<<g1024, 256, 0, stream>>>(zbf, w1T, b1, nullptr, nullptr, hbf, L_NODES, HID, CDIM, 1);
    gemm_bf16_kernel<<<g512, 256, 0, stream>>>(hbf, w2T, b2, x1f, (float*)d_out, nullptr, L_NODES, CDIM, HID, 0);
}